// Round 1
// baseline (412.388 us; speedup 1.0000x reference)
//
#include <hip/hip_runtime.h>
#include <hip/hip_fp16.h>

#define NCTX 5952
#define NHEAD 16
#define MT 93   // NCTX / 64

typedef _Float16 f16x8 __attribute__((ext_vector_type(8)));
typedef _Float16 f16x4 __attribute__((ext_vector_type(4)));
typedef float    f32x4 __attribute__((ext_vector_type(4)));

__device__ __forceinline__ f32x4 mfma16(f16x8 a, f16x8 b, f32x4 c) {
    return __builtin_amdgcn_mfma_f32_16x16x32_f16(a, b, c, 0, 0, 0);
}

// cumulative 64-row tiles per sequence: lengths/64 = {8,9,10,11,12,13,14,16}
__device__ const int kCT[9] = {0, 8, 17, 27, 38, 50, 63, 77, 93};

// C = A[M,1024] @ W[N,1024]^T (+bias). Split-f16 (hi+lo) staging for ~fp32 accuracy.
// MODE 0: N=3072 (Wq|Wk|Wv); epilogue writes q,k head-major f16 and v d-major f16.
// MODE 1: N=1024 (Wo); epilogue writes fp32 out + bo.
template <int MODE>
__global__ __launch_bounds__(256) void gemm_split(
    const float* __restrict__ A,
    const float* __restrict__ W0, const float* __restrict__ W1, const float* __restrict__ W2,
    const float* __restrict__ bias0, const float* __restrict__ bias1,
    _Float16* __restrict__ qh, _Float16* __restrict__ kh, _Float16* __restrict__ vt,
    float* __restrict__ outp)
{
    __shared__ alignas(16) _Float16 Ah[64][72];
    __shared__ alignas(16) _Float16 Al[64][72];
    __shared__ alignas(16) _Float16 Bh[64][72];
    __shared__ alignas(16) _Float16 Bl[64][72];

    const int bid = blockIdx.x;
    const int mt = bid % MT, nt = bid / MT;
    const int m0 = mt * 64, n0 = nt * 64;
    const int tid = threadIdx.x;
    const int l  = tid & 63;
    const int wr = ((tid >> 6) >> 1) * 32;   // wave row quadrant
    const int wc = ((tid >> 6) & 1) * 32;    // wave col quadrant
    const int ls = l >> 4, lq = l & 15;

    const int srow = tid >> 2;           // staging row 0..63
    const int scol = (tid & 3) << 4;     // staging col {0,16,32,48}

    const float* aptr = A + (size_t)(m0 + srow) * 1024 + scol;
    const float* wptr;
    {
        int nrow = n0 + srow;
        const float* wsel = W0;
        if (MODE == 0) {
            if (nrow >= 2048)      { wsel = W2; nrow -= 2048; }
            else if (nrow >= 1024) { wsel = W1; nrow -= 1024; }
        }
        wptr = wsel + (size_t)nrow * 1024 + scol;
    }

    f32x4 acc[2][2] = {};

    for (int k0 = 0; k0 < 1024; k0 += 64) {
        f32x4 areg[4], breg[4];
        #pragma unroll
        for (int j = 0; j < 4; ++j) areg[j] = *(const f32x4*)(aptr + k0 + 4 * j);
        #pragma unroll
        for (int j = 0; j < 4; ++j) breg[j] = *(const f32x4*)(wptr + k0 + 4 * j);

        __syncthreads();   // previous iteration's reads done before overwrite
        #pragma unroll
        for (int hf = 0; hf < 2; ++hf) {
            f16x8 hi, lo;
            #pragma unroll
            for (int e = 0; e < 8; ++e) {
                float xv = areg[hf * 2 + (e >> 2)][e & 3];
                _Float16 hv = (_Float16)xv;
                hi[e] = hv;
                lo[e] = (_Float16)(xv - (float)hv);
            }
            *(f16x8*)&Ah[srow][scol + hf * 8] = hi;
            *(f16x8*)&Al[srow][scol + hf * 8] = lo;
            #pragma unroll
            for (int e = 0; e < 8; ++e) {
                float xv = breg[hf * 2 + (e >> 2)][e & 3];
                _Float16 hv = (_Float16)xv;
                hi[e] = hv;
                lo[e] = (_Float16)(xv - (float)hv);
            }
            *(f16x8*)&Bh[srow][scol + hf * 8] = hi;
            *(f16x8*)&Bl[srow][scol + hf * 8] = lo;
        }
        __syncthreads();

        #pragma unroll
        for (int kc = 0; kc < 2; ++kc) {
            f16x8 a_h[2], a_l[2], b_h[2], b_l[2];
            #pragma unroll
            for (int i = 0; i < 2; ++i) {
                a_h[i] = *(const f16x8*)&Ah[wr + 16 * i + lq][kc * 32 + ls * 8];
                a_l[i] = *(const f16x8*)&Al[wr + 16 * i + lq][kc * 32 + ls * 8];
                b_h[i] = *(const f16x8*)&Bh[wc + 16 * i + lq][kc * 32 + ls * 8];
                b_l[i] = *(const f16x8*)&Bl[wc + 16 * i + lq][kc * 32 + ls * 8];
            }
            #pragma unroll
            for (int i = 0; i < 2; ++i)
                #pragma unroll
                for (int j = 0; j < 2; ++j) {
                    acc[i][j] = mfma16(a_h[i], b_h[j], acc[i][j]);
                    acc[i][j] = mfma16(a_h[i], b_l[j], acc[i][j]);
                    acc[i][j] = mfma16(a_l[i], b_h[j], acc[i][j]);
                }
        }
    }

    // C/D layout (m89-verified): col = lane&15, row = (lane>>4)*4 + reg
    #pragma unroll
    for (int i = 0; i < 2; ++i)
        #pragma unroll
        for (int j = 0; j < 2; ++j)
            #pragma unroll
            for (int r = 0; r < 4; ++r) {
                const int m = m0 + wr + 16 * i + 4 * ls + r;
                const int n = n0 + wc + 16 * j + lq;
                float v = acc[i][j][r];
                if (MODE == 0) {
                    const int which = n >> 10, nn = n & 1023;
                    const int hh = nn >> 6, dd = nn & 63;
                    if (which == 0) {
                        v += bias0[nn];
                        qh[((size_t)hh * NCTX + m) * 64 + dd] = (_Float16)v;
                    } else if (which == 1) {
                        kh[((size_t)hh * NCTX + m) * 64 + dd] = (_Float16)v;
                    } else {
                        v += bias1[nn];
                        vt[((size_t)hh * 64 + dd) * NCTX + m] = (_Float16)v;  // d-major
                    }
                } else {
                    outp[(size_t)m * 1024 + n] = v + bias0[n];
                }
            }
}

// Flash-style (no-max: scores bounded) varlen attention.
// Block = (qtile64, head); 4 waves x 16 q-rows. S^T = mfma(K,Q) so col=lane&15=q.
__global__ __launch_bounds__(256) void attn_kernel(
    const _Float16* __restrict__ qh, const _Float16* __restrict__ kh,
    const _Float16* __restrict__ vt, float* __restrict__ ctx)
{
    __shared__ alignas(16) _Float16 P[4][16][80];   // per-wave P tile, +16 f16 pad
    const int bid = blockIdx.x;
    const int h = bid & 15, t = bid >> 4;
    int b = 0;
    while (t >= kCT[b + 1]) ++b;
    const int kbase = kCT[b] * 64;
    const int L = (kCT[b + 1] - kCT[b]) * 64;
    const int w = threadIdx.x >> 6, l = threadIdx.x & 63;
    const int ls = l >> 4, lq = l & 15;
    const int q0 = t * 64 + w * 16;

    const _Float16* qp = qh + ((size_t)h * NCTX + q0 + lq) * 64 + ls * 8;
    const f16x8 qf0 = *(const f16x8*)qp;
    const f16x8 qf1 = *(const f16x8*)(qp + 32);

    const _Float16* kb = kh + (size_t)h * NCTX * 64;
    const _Float16* vb = vt + (size_t)h * 64 * NCTX;

    f32x4 acc[4] = {};
    float lsum = 0.f;

    for (int kv = 0; kv < L; kv += 64) {
        // S^T tiles: rows = keys (16 per group), col = q = lane&15
        f32x4 s[4];
        #pragma unroll
        for (int g = 0; g < 4; ++g) {
            const _Float16* kp = kb + (size_t)(kbase + kv + g * 16 + lq) * 64 + ls * 8;
            f16x8 k0v = *(const f16x8*)kp;
            f16x8 k1v = *(const f16x8*)(kp + 32);
            f32x4 z = {};
            z = mfma16(k0v, qf0, z);
            z = mfma16(k1v, qf1, z);
            s[g] = z;
        }
        // exp (scores bounded, skip max subtraction); lane's 16 vals share q=lq
        float tsum = 0.f;
        #pragma unroll
        for (int g = 0; g < 4; ++g) {
            f16x4 ph;
            #pragma unroll
            for (int r = 0; r < 4; ++r) {
                float p = __expf(s[g][r] * 0.125f);
                tsum += p;
                ph[r] = (_Float16)p;
            }
            // key = g*16 + 4*ls + r  ->  P[q][key]
            *(f16x4*)&P[w][lq][g * 16 + ls * 4] = ph;
        }
        tsum += __shfl_xor(tsum, 16, 64);
        tsum += __shfl_xor(tsum, 32, 64);
        lsum += tsum;
        // ctx^T += V^T @ P^T   (A-frag: vt d-major contiguous; B-frag: P row b128)
        #pragma unroll
        for (int c = 0; c < 2; ++c) {
            f16x8 pf = *(const f16x8*)&P[w][lq][c * 32 + ls * 8];
            #pragma unroll
            for (int dg = 0; dg < 4; ++dg) {
                const _Float16* vp = vb + (size_t)(dg * 16 + lq) * NCTX + kbase + kv + c * 32 + ls * 8;
                f16x8 vf = *(const f16x8*)vp;
                acc[dg] = mfma16(vf, pf, acc[dg]);
            }
        }
    }

    const float inv = 1.f / lsum;
    float* cp = ctx + (size_t)(q0 + lq) * 1024 + h * 64;
    #pragma unroll
    for (int dg = 0; dg < 4; ++dg)
        #pragma unroll
        for (int r = 0; r < 4; ++r)
            cp[dg * 16 + 4 * ls + r] = acc[dg][r] * inv;
}

extern "C" void kernel_launch(void* const* d_in, const int* in_sizes, int n_in,
                              void* d_out, int out_size, void* d_ws, size_t ws_size,
                              hipStream_t stream)
{
    const float* x  = (const float*)d_in[0];
    const float* Wq = (const float*)d_in[1];
    const float* bq = (const float*)d_in[2];
    const float* Wk = (const float*)d_in[3];
    const float* Wv = (const float*)d_in[4];
    const float* bv = (const float*)d_in[5];
    const float* Wo = (const float*)d_in[6];
    const float* bo = (const float*)d_in[7];
    float* out = (float*)d_out;

    char* p = (char*)d_ws;
    _Float16* qh = (_Float16*)p; p += (size_t)NHEAD * NCTX * 64 * 2;
    _Float16* kh = (_Float16*)p; p += (size_t)NHEAD * NCTX * 64 * 2;
    _Float16* vt = (_Float16*)p; p += (size_t)NHEAD * NCTX * 64 * 2;
    float*   ctx = (float*)p;    p += (size_t)NCTX * 1024 * 4;
    // total ws use: ~58.2 MiB

    gemm_split<0><<<dim3(MT * 48), 256, 0, stream>>>(
        x, Wq, Wk, Wv, bq, bv, qh, kh, vt, nullptr);
    attn_kernel<<<dim3(MT * 16), 256, 0, stream>>>(qh, kh, vt, ctx);
    gemm_split<1><<<dim3(MT * 16), 256, 0, stream>>>(
        ctx, Wo, nullptr, nullptr, bo, nullptr, nullptr, nullptr, nullptr, out);
}

// Round 2
// 387.001 us; speedup vs baseline: 1.0656x; 1.0656x over previous
//
#include <hip/hip_runtime.h>
#include <hip/hip_fp16.h>
#include <stdint.h>

#define NCTX 5952
#define MPAD 6144
#define NHEAD 16

typedef _Float16 f16x8 __attribute__((ext_vector_type(8)));
typedef _Float16 f16x4 __attribute__((ext_vector_type(4)));
typedef float    f32x4 __attribute__((ext_vector_type(4)));

typedef const __attribute__((address_space(1))) void* gp1;
typedef __attribute__((address_space(3))) void* lp3;

__device__ __forceinline__ f32x4 mfma16(f16x8 a, f16x8 b, f32x4 c) {
    return __builtin_amdgcn_mfma_f32_16x16x32_f16(a, b, c, 0, 0, 0);
}

__device__ const int kCT[9] = {0, 8, 17, 27, 38, 50, 63, 77, 93};

// ---- pre-split passes: fp32 -> f16 hi/lo, duplicated-K layout, granule-swizzled ----
// logical col k in [0,1024): storage granule within 64-block XORed with (row&7).
// A' = [hi | hi | lo], B' = [hi | lo | hi]  (K=3072; block0: Ah*Bh, 1: Ah*Bl, 2: Al*Bh)

__global__ __launch_bounds__(256) void presplit_A(const float* __restrict__ x,
                                                  _Float16* __restrict__ A2) {
    int idx = blockIdx.x * 256 + threadIdx.x;      // MPAD * 128
    int m = idx >> 7, k8 = (idx & 127) << 3;
    f16x8 hi = {}, lo = {};
    if (m < NCTX) {
        const float* xp = x + (size_t)m * 1024 + k8;
        #pragma unroll
        for (int e = 0; e < 8; ++e) {
            float v = xp[e];
            _Float16 h = (_Float16)v;
            hi[e] = h; lo[e] = (_Float16)(v - (float)h);
        }
    }
    int c = (k8 & ~63) | ((((k8 >> 3) & 7) ^ (m & 7)) << 3);
    _Float16* p = A2 + (size_t)m * 3072 + c;
    *(f16x8*)(p)        = hi;
    *(f16x8*)(p + 1024) = hi;
    *(f16x8*)(p + 2048) = lo;
}

__global__ __launch_bounds__(256) void presplit_W(
    const float* __restrict__ Wq, const float* __restrict__ Wk,
    const float* __restrict__ Wv, const float* __restrict__ Wo,
    _Float16* __restrict__ W2) {
    int idx = blockIdx.x * 256 + threadIdx.x;      // 4096 * 128
    int n = idx >> 7, k8 = (idx & 127) << 3;
    const float* src = (n < 1024) ? Wq : (n < 2048) ? Wk : (n < 3072) ? Wv : Wo;
    const float* xp = src + (size_t)(n & 1023) * 1024 + k8;
    f16x8 hi, lo;
    #pragma unroll
    for (int e = 0; e < 8; ++e) {
        float v = xp[e];
        _Float16 h = (_Float16)v;
        hi[e] = h; lo[e] = (_Float16)(v - (float)h);
    }
    int c = (k8 & ~63) | ((((k8 >> 3) & 7) ^ (n & 7)) << 3);
    _Float16* p = W2 + (size_t)n * 3072 + c;
    *(f16x8*)(p)        = hi;
    *(f16x8*)(p + 1024) = lo;
    *(f16x8*)(p + 2048) = hi;
}

// ---- plain f16 GEMM, K=3072, m97 structure: global_load_lds + 2-barrier K-loop ----
// MODE 0: A2x[6144] x W2 rows [0,3072)   -> q/k/v f16 epilogue   (BM=128)
// MODE 1: A2o[6144] x W2 rows [3072,4096) -> fp32 out + bo       (BM=64)
template <int MODE>
__global__ __launch_bounds__(256) void gemm_f16(
    const _Float16* __restrict__ A2, const _Float16* __restrict__ W2,
    const float* __restrict__ bq, const float* __restrict__ bv, const float* __restrict__ bo,
    _Float16* __restrict__ qh, _Float16* __restrict__ kh, _Float16* __restrict__ vt,
    float* __restrict__ outp)
{
    constexpr int BM  = (MODE == 0) ? 128 : 64;
    constexpr int MI  = BM / 32;              // A-frags per wave
    constexpr int NT  = (MODE == 0) ? 24 : 8; // N-tiles (BN=128)
    constexpr int MTt = MPAD / BM;

    __shared__ alignas(16) _Float16 As[BM][64];
    __shared__ alignas(16) _Float16 Bs[128][64];

    int bid = blockIdx.x;
    {   // bijective XCD swizzle (grid divisible by 8)
        constexpr int cpx = (MTt * NT) / 8;
        bid = (bid & 7) * cpx + (bid >> 3);
    }
    const int mt = bid % MTt, nt = bid / MTt;
    const int m0 = mt * BM, n0 = nt * 128;
    const int tid = threadIdx.x;
    const int w = tid >> 6, l = tid & 63;
    const int ls = l >> 4, lq = l & 15;
    const int wr = (w >> 1) * (BM / 2), wc = (w & 1) * 64;

    const _Float16* ag = A2 + (size_t)(m0 + (tid >> 3)) * 3072 + ((tid & 7) << 3);
    const _Float16* bg = W2 + (size_t)((MODE ? 3072 : 0) + n0 + (tid >> 3)) * 3072 + ((tid & 7) << 3);
    char* aldsb = (char*)&As[0][0] + (size_t)(w * 8) * 128;
    char* bldsb = (char*)&Bs[0][0] + (size_t)(w * 8) * 128;

    f32x4 acc[MI][4] = {};

    for (int k0 = 0; k0 < 3072; k0 += 64) {
        #pragma unroll
        for (int i = 0; i < BM / 32; ++i)
            __builtin_amdgcn_global_load_lds((gp1)(ag + (size_t)(i * 32) * 3072 + k0),
                                             (lp3)(aldsb + i * 32 * 128), 16, 0, 0);
        #pragma unroll
        for (int i = 0; i < 4; ++i)
            __builtin_amdgcn_global_load_lds((gp1)(bg + (size_t)(i * 32) * 3072 + k0),
                                             (lp3)(bldsb + i * 32 * 128), 16, 0, 0);
        __syncthreads();   // drains vmcnt -> LDS tiles valid

        #pragma unroll
        for (int kc = 0; kc < 2; ++kc) {
            f16x8 af[MI], bf[4];
            #pragma unroll
            for (int i = 0; i < MI; ++i) {
                int ar = wr + 16 * i + lq;
                af[i] = *(const f16x8*)&As[ar][((kc * 4 + ls) ^ (ar & 7)) << 3];
            }
            #pragma unroll
            for (int j = 0; j < 4; ++j) {
                int br = wc + 16 * j + lq;
                bf[j] = *(const f16x8*)&Bs[br][((kc * 4 + ls) ^ (br & 7)) << 3];
            }
            #pragma unroll
            for (int i = 0; i < MI; ++i)
                #pragma unroll
                for (int j = 0; j < 4; ++j)
                    acc[i][j] = mfma16(af[i], bf[j], acc[i][j]);
        }
        __syncthreads();   // all reads done before next overwrite
    }

    #pragma unroll
    for (int i = 0; i < MI; ++i)
        #pragma unroll
        for (int j = 0; j < 4; ++j)
            #pragma unroll
            for (int r = 0; r < 4; ++r) {
                const int m = m0 + wr + 16 * i + 4 * ls + r;
                if (m >= NCTX) continue;
                const int n = n0 + wc + 16 * j + lq;
                float v = acc[i][j][r];
                if (MODE == 0) {
                    const int which = n >> 10, nn = n & 1023;
                    const int hh = nn >> 6, dd = nn & 63;
                    if (which == 0) {
                        v += bq[nn];
                        qh[((size_t)hh * NCTX + m) * 64 + dd] = (_Float16)v;
                    } else if (which == 1) {
                        kh[((size_t)hh * NCTX + m) * 64 + dd] = (_Float16)v;
                    } else {
                        v += bv[nn];
                        vt[((size_t)hh * 64 + dd) * NCTX + m] = (_Float16)v;  // d-major
                    }
                } else {
                    outp[(size_t)m * 1024 + n] = v + bo[n];
                }
            }
}

// ---- flash attention (no-max), 2 waves x 32 q-rows, swizzled wave-private P ----
__global__ __launch_bounds__(128) void attn_kernel(
    const _Float16* __restrict__ qh, const _Float16* __restrict__ kh,
    const _Float16* __restrict__ vt, _Float16* __restrict__ A2o)
{
    __shared__ alignas(16) _Float16 P[2][2][16][64];
    const int bid = blockIdx.x;
    const int h = bid & 15, t = bid >> 4;
    int b = 0;
    while (t >= kCT[b + 1]) ++b;
    const int kbase = kCT[b] * 64;
    const int L = (kCT[b + 1] - kCT[b]) * 64;
    const int w = threadIdx.x >> 6, l = threadIdx.x & 63;
    const int ls = l >> 4, lq = l & 15;
    const int q0 = t * 64 + w * 32;

    f16x8 qf[2][2];
    #pragma unroll
    for (int qg = 0; qg < 2; ++qg) {
        const _Float16* qp = qh + ((size_t)h * NCTX + q0 + qg * 16 + lq) * 64 + ls * 8;
        qf[qg][0] = *(const f16x8*)qp;
        qf[qg][1] = *(const f16x8*)(qp + 32);
    }
    const _Float16* kb = kh + (size_t)h * NCTX * 64;
    const _Float16* vb = vt + (size_t)h * 64 * NCTX;

    f32x4 acc[2][4] = {};
    float lsum[2] = {0.f, 0.f};

    for (int kv = 0; kv < L; kv += 64) {
        f32x4 s[2][4];
        #pragma unroll
        for (int g = 0; g < 4; ++g) {
            const _Float16* kp = kb + (size_t)(kbase + kv + g * 16 + lq) * 64 + ls * 8;
            f16x8 kf0 = *(const f16x8*)kp;
            f16x8 kf1 = *(const f16x8*)(kp + 32);
            #pragma unroll
            for (int qg = 0; qg < 2; ++qg) {
                f32x4 z = {};
                z = mfma16(kf0, qf[qg][0], z);
                z = mfma16(kf1, qf[qg][1], z);
                s[qg][g] = z;   // S^T: row=key g*16+4ls+r, col=q=lq
            }
        }
        #pragma unroll
        for (int qg = 0; qg < 2; ++qg) {
            float tsum = 0.f;
            #pragma unroll
            for (int g = 0; g < 4; ++g) {
                f16x4 ph;
                #pragma unroll
                for (int r = 0; r < 4; ++r) {
                    float pv = __expf(s[qg][g][r] * 0.125f);
                    tsum += pv;
                    ph[r] = (_Float16)pv;
                }
                int gi = 2 * g + (ls >> 1);   // logical 8-f16 granule of key block
                *(f16x4*)&P[w][qg][lq][(((gi ^ (lq & 7)) << 3) | ((ls & 1) << 2))] = ph;
            }
            tsum += __shfl_xor(tsum, 16, 64);
            tsum += __shfl_xor(tsum, 32, 64);
            lsum[qg] += tsum;
        }
        // ctx^T += V^T @ P^T
        #pragma unroll
        for (int c = 0; c < 2; ++c) {
            f16x8 pf[2];
            #pragma unroll
            for (int qg = 0; qg < 2; ++qg)
                pf[qg] = *(const f16x8*)&P[w][qg][lq][((4 * c + ls) ^ (lq & 7)) << 3];
            #pragma unroll
            for (int dg = 0; dg < 4; ++dg) {
                const _Float16* vp = vb + (size_t)(dg * 16 + lq) * NCTX + kbase + kv + c * 32 + ls * 8;
                f16x8 vf = *(const f16x8*)vp;
                #pragma unroll
                for (int qg = 0; qg < 2; ++qg)
                    acc[qg][dg] = mfma16(vf, pf[qg], acc[qg][dg]);
            }
        }
    }

    // epilogue: write ctx directly in the pre-split duplicated/swizzled layout
    #pragma unroll
    for (int qg = 0; qg < 2; ++qg) {
        const float inv = 1.f / lsum[qg];
        const int m = q0 + qg * 16 + lq;      // ctx^T col = q = lq
        _Float16* rowp = A2o + (size_t)m * 3072;
        #pragma unroll
        for (int dg = 0; dg < 4; ++dg) {
            f16x4 ch, cl;
            #pragma unroll
            for (int r = 0; r < 4; ++r) {
                float v = acc[qg][dg][r] * inv;
                _Float16 hh = (_Float16)v;
                ch[r] = hh; cl[r] = (_Float16)(v - (float)hh);
            }
            int g = 2 * dg + (ls >> 1);
            int c0 = (h << 6) | ((g ^ (m & 7)) << 3) | ((ls & 1) << 2);
            *(f16x4*)(rowp + c0)        = ch;
            *(f16x4*)(rowp + 1024 + c0) = ch;
            *(f16x4*)(rowp + 2048 + c0) = cl;
        }
    }
}

extern "C" void kernel_launch(void* const* d_in, const int* in_sizes, int n_in,
                              void* d_out, int out_size, void* d_ws, size_t ws_size,
                              hipStream_t stream)
{
    const float* x  = (const float*)d_in[0];
    const float* Wq = (const float*)d_in[1];
    const float* bq = (const float*)d_in[2];
    const float* Wk = (const float*)d_in[3];
    const float* Wv = (const float*)d_in[4];
    const float* bv = (const float*)d_in[5];
    const float* Wo = (const float*)d_in[6];
    const float* bo = (const float*)d_in[7];
    float* out = (float*)d_out;

    char* p = (char*)d_ws;
    _Float16* A2x = (_Float16*)p; p += (size_t)MPAD * 3072 * 2;
    _Float16* W2  = (_Float16*)p; p += (size_t)4096 * 3072 * 2;
    _Float16* qh  = (_Float16*)p; p += (size_t)NHEAD * NCTX * 64 * 2;
    _Float16* kh  = (_Float16*)p; p += (size_t)NHEAD * NCTX * 64 * 2;
    _Float16* vt  = (_Float16*)p; p += (size_t)NHEAD * NCTX * 64 * 2;
    _Float16* A2o = (_Float16*)p; p += (size_t)MPAD * 3072 * 2;
    // total ~131 MiB

    presplit_A<<<dim3(MPAD * 128 / 256), 256, 0, stream>>>(x, A2x);
    presplit_W<<<dim3(4096 * 128 / 256), 256, 0, stream>>>(Wq, Wk, Wv, Wo, W2);
    gemm_f16<0><<<dim3(48 * 24), 256, 0, stream>>>(A2x, W2, bq, bv, nullptr,
                                                   qh, kh, vt, nullptr);
    attn_kernel<<<dim3(93 * 16), 128, 0, stream>>>(qh, kh, vt, A2o);
    gemm_f16<1><<<dim3(96 * 8), 256, 0, stream>>>(A2o, W2, nullptr, nullptr, bo,
                                                  nullptr, nullptr, nullptr, out);
}

// Round 3
// 359.343 us; speedup vs baseline: 1.1476x; 1.0770x over previous
//
#include <hip/hip_runtime.h>
#include <hip/hip_fp16.h>
#include <stdint.h>

#define NCTX 5952
#define MPAD 6144
#define NHEAD 16

typedef _Float16 f16x8 __attribute__((ext_vector_type(8)));
typedef _Float16 f16x4 __attribute__((ext_vector_type(4)));
typedef float    f32x4 __attribute__((ext_vector_type(4)));

typedef const __attribute__((address_space(1))) void* gp1;
typedef __attribute__((address_space(3))) void* lp3;

__device__ __forceinline__ f32x4 mfma16(f16x8 a, f16x8 b, f32x4 c) {
    return __builtin_amdgcn_mfma_f32_16x16x32_f16(a, b, c, 0, 0, 0);
}

#define SBAR() do { __builtin_amdgcn_sched_barrier(0); \
                    __builtin_amdgcn_s_barrier();      \
                    __builtin_amdgcn_sched_barrier(0); } while (0)

// per-seq tables: lengths {512,576,640,704,768,832,896,1024}
__device__ const int kQT[9]    = {0, 4, 9, 14, 20, 26, 33, 40, 48}; // cum 128-row q-tiles
__device__ const int kBASE8[8] = {0, 512, 1088, 1728, 2432, 3200, 4032, 4928};
__device__ const int kLEN[8]   = {512, 576, 640, 704, 768, 832, 896, 1024};

// ---- pre-split: fp32 -> f16 hi/lo, duplicated-K layout, granule-swizzled ----
// A' = [hi|hi|lo], B' = [hi|lo|hi]  (K=3072: Ah*Bh + Ah*Bl + Al*Bh)
__global__ __launch_bounds__(256) void presplit_A(const float* __restrict__ x,
                                                  _Float16* __restrict__ A2) {
    int idx = blockIdx.x * 256 + threadIdx.x;      // MPAD * 128
    int m = idx >> 7, k8 = (idx & 127) << 3;
    f16x8 hi = {}, lo = {};
    if (m < NCTX) {
        const float* xp = x + (size_t)m * 1024 + k8;
        #pragma unroll
        for (int e = 0; e < 8; ++e) {
            float v = xp[e];
            _Float16 h = (_Float16)v;
            hi[e] = h; lo[e] = (_Float16)(v - (float)h);
        }
    }
    int c = (k8 & ~63) | ((((k8 >> 3) & 7) ^ (m & 7)) << 3);
    _Float16* p = A2 + (size_t)m * 3072 + c;
    *(f16x8*)(p)        = hi;
    *(f16x8*)(p + 1024) = hi;
    *(f16x8*)(p + 2048) = lo;
}

__global__ __launch_bounds__(256) void presplit_W(
    const float* __restrict__ Wq, const float* __restrict__ Wk,
    const float* __restrict__ Wv, const float* __restrict__ Wo,
    _Float16* __restrict__ W2) {
    int idx = blockIdx.x * 256 + threadIdx.x;      // 4096 * 128
    int n = idx >> 7, k8 = (idx & 127) << 3;
    const float* src = (n < 1024) ? Wq : (n < 2048) ? Wk : (n < 3072) ? Wv : Wo;
    const float* xp = src + (size_t)(n & 1023) * 1024 + k8;
    f16x8 hi, lo;
    #pragma unroll
    for (int e = 0; e < 8; ++e) {
        float v = xp[e];
        _Float16 h = (_Float16)v;
        hi[e] = h; lo[e] = (_Float16)(v - (float)h);
    }
    int c = (k8 & ~63) | ((((k8 >> 3) & 7) ^ (n & 7)) << 3);
    _Float16* p = W2 + (size_t)n * 3072 + c;
    *(f16x8*)(p)        = hi;
    *(f16x8*)(p + 1024) = lo;
    *(f16x8*)(p + 2048) = hi;
}

// ---- pipelined GEMM: 3 LDS buffers, counted vmcnt, 2 phases/K-tile, 8 waves ----
// MODE 0: BM=256 BN=96,  grid 24x32=768 (=3.0 rounds), q/k/v epilogue
// MODE 1: BM=256 BN=128, grid 24x8 =192 (<1 round),    fp32 out + bo
template <int MODE>
__global__ __launch_bounds__(512) void gemm8(
    const _Float16* __restrict__ A2, const _Float16* __restrict__ W2,
    const float* __restrict__ bq, const float* __restrict__ bv, const float* __restrict__ bo,
    _Float16* __restrict__ qh, _Float16* __restrict__ kh, _Float16* __restrict__ vt,
    float* __restrict__ outp)
{
    constexpr int BN = (MODE == 0) ? 96 : 128;
    constexpr int NF = BN / 32;                 // n-frags per wave (wave grid 4Mx2N)
    constexpr int NT = (MODE == 0) ? 32 : 8;
    constexpr int T  = 48;                      // K-tiles (K=3072, BK=64)

    __shared__ alignas(16) _Float16 As[3][256][64];   // 96 KiB
    __shared__ alignas(16) _Float16 Bs[3][128][64];   // 48 KiB

    int bid = blockIdx.x;
    constexpr int cpx = (24 * NT) / 8;
    bid = (bid & 7) * cpx + (bid >> 3);         // bijective XCD swizzle
    const int mt = bid % 24, nt = bid / 24;
    const int m0 = mt * 256, n0 = nt * BN;
    const int tid = threadIdx.x;
    const int w = tid >> 6, l = tid & 63;
    const int ls = l >> 4, lq = l & 15;
    const int wm = w >> 1, wn = w & 1;

    const _Float16* ag = A2 + (size_t)(m0 + (tid >> 3)) * 3072 + ((tid & 7) << 3);
    const _Float16* bg = W2 + (size_t)((MODE ? 3072 : 0) + n0 + (tid >> 3)) * 3072 + ((tid & 7) << 3);
    char* ab = (char*)&As[0][0][0] + (size_t)(w * 8) * 128;
    char* bb = (char*)&Bs[0][0][0] + (size_t)(w * 8) * 128;

    // stage instr: 512 lanes x 16B = 8KB = 64 rows; A needs 4, B needs 2 (rows 96..127 junk at BN=96)
    auto stA = [&](int buf, int tile, int i) {
        __builtin_amdgcn_global_load_lds((gp1)(ag + (size_t)(i * 64) * 3072 + tile * 64),
                                         (lp3)(ab + buf * 32768 + i * 8192), 16, 0, 0);
    };
    auto stB = [&](int buf, int tile, int i) {
        __builtin_amdgcn_global_load_lds((gp1)(bg + (size_t)(i * 64) * 3072 + tile * 64),
                                         (lp3)(bb + buf * 16384 + i * 8192), 16, 0, 0);
    };
    auto ldA = [&](int buf, int fm, int kc) {
        const int r = wm * 64 + fm * 16 + lq;
        return *(const f16x8*)&As[buf][r][((kc * 4 + ls) ^ (lq & 7)) << 3];
    };
    auto ldB = [&](int buf, int fn, int kc) {
        const int r = wn * (16 * NF) + fn * 16 + lq;
        return *(const f16x8*)&Bs[buf][r][((kc * 4 + ls) ^ (lq & 7)) << 3];
    };

    f32x4 acc[4][NF] = {};

    // prologue: stage tiles 0,1 -> bufs 0,1; wait tile0 (12 issued, keep 6 in flight)
    #pragma unroll
    for (int pt = 0; pt < 2; ++pt) {
        #pragma unroll
        for (int i = 0; i < 4; ++i) stA(pt, pt, i);
        #pragma unroll
        for (int i = 0; i < 2; ++i) stB(pt, pt, i);
    }
    asm volatile("s_waitcnt vmcnt(6)" ::: "memory");
    SBAR();

    int cb = 0, pb = 2;
    #pragma unroll 1
    for (int t = 0; t < T; ++t) {
        const bool pf = (t + 2 < T);
        f16x8 a[4], b[NF];
        // ---- phase 0 (kc=0): ds_read frags | issue 3 gloads of tile t+2 | barrier | MFMA ----
        #pragma unroll
        for (int i = 0; i < 4; ++i) a[i] = ldA(cb, i, 0);
        #pragma unroll
        for (int j = 0; j < NF; ++j) b[j] = ldB(cb, j, 0);
        if (pf) { stA(pb, t + 2, 0); stA(pb, t + 2, 1); stA(pb, t + 2, 2); }
        SBAR();
        __builtin_amdgcn_s_setprio(1);
        #pragma unroll
        for (int i = 0; i < 4; ++i)
            #pragma unroll
            for (int j = 0; j < NF; ++j)
                acc[i][j] = mfma16(a[i], b[j], acc[i][j]);
        __builtin_amdgcn_s_setprio(0);
        SBAR();
        // ---- phase 1 (kc=1): ds_read | 3 gloads | barrier | MFMA | counted vmcnt ----
        #pragma unroll
        for (int i = 0; i < 4; ++i) a[i] = ldA(cb, i, 1);
        #pragma unroll
        for (int j = 0; j < NF; ++j) b[j] = ldB(cb, j, 1);
        if (pf) { stA(pb, t + 2, 3); stB(pb, t + 2, 0); stB(pb, t + 2, 1); }
        SBAR();
        __builtin_amdgcn_s_setprio(1);
        #pragma unroll
        for (int i = 0; i < 4; ++i)
            #pragma unroll
            for (int j = 0; j < NF; ++j)
                acc[i][j] = mfma16(a[i], b[j], acc[i][j]);
        __builtin_amdgcn_s_setprio(0);
        // tile t+1 must be resident before next iteration's ds_reads; never drain to 0 mid-loop
        if (pf) asm volatile("s_waitcnt vmcnt(6)" ::: "memory");
        else    asm volatile("s_waitcnt vmcnt(0)" ::: "memory");
        SBAR();
        cb = (cb == 2) ? 0 : cb + 1;
        pb = (pb == 2) ? 0 : pb + 1;
    }

    // C/D layout: col = lane&15, row = (lane>>4)*4 + reg
    #pragma unroll
    for (int i = 0; i < 4; ++i)
        #pragma unroll
        for (int j = 0; j < NF; ++j)
            #pragma unroll
            for (int r = 0; r < 4; ++r) {
                const int m = m0 + wm * 64 + i * 16 + 4 * ls + r;
                if (m >= NCTX) continue;
                const int n = n0 + wn * (16 * NF) + j * 16 + lq;
                float v = acc[i][j][r];
                if (MODE == 0) {
                    const int which = n >> 10, nn = n & 1023;
                    const int hh = nn >> 6, dd = nn & 63;
                    if (which == 0) {
                        v += bq[nn];
                        qh[((size_t)hh * NCTX + m) * 64 + dd] = (_Float16)v;
                    } else if (which == 1) {
                        kh[((size_t)hh * NCTX + m) * 64 + dd] = (_Float16)v;
                    } else {
                        v += bv[nn];
                        vt[((size_t)hh * 64 + dd) * NCTX + m] = (_Float16)v;  // d-major
                    }
                } else {
                    outp[(size_t)m * 1024 + n] = v + bo[n];
                }
            }
}

// ---- flash attention (no-max), 4 waves x 32 q-rows per 128-row tile ----
__global__ __launch_bounds__(256) void attn_kernel(
    const _Float16* __restrict__ qh, const _Float16* __restrict__ kh,
    const _Float16* __restrict__ vt, _Float16* __restrict__ A2o)
{
    __shared__ alignas(16) _Float16 P[4][2][16][64];
    const int bid = blockIdx.x;
    const int h = bid & 15, t = bid >> 4;
    int b = 0;
    while (t >= kQT[b + 1]) ++b;
    const int kbase = kBASE8[b];
    const int L = kLEN[b];
    const int w = threadIdx.x >> 6, l = threadIdx.x & 63;
    const int ls = l >> 4, lq = l & 15;
    const int q0l = (t - kQT[b]) * 128 + w * 32;
    if (q0l >= L) return;          // tail waves of ragged tiles; no barriers below
    const int q0 = kbase + q0l;

    f16x8 qf[2][2];
    #pragma unroll
    for (int qg = 0; qg < 2; ++qg) {
        const _Float16* qp = qh + ((size_t)h * NCTX + q0 + qg * 16 + lq) * 64 + ls * 8;
        qf[qg][0] = *(const f16x8*)qp;
        qf[qg][1] = *(const f16x8*)(qp + 32);
    }
    const _Float16* kb = kh + (size_t)h * NCTX * 64;
    const _Float16* vb = vt + (size_t)h * 64 * NCTX;

    f32x4 acc[2][4] = {};
    float lsum[2] = {0.f, 0.f};

    for (int kv = 0; kv < L; kv += 64) {
        f32x4 s[2][4];
        __builtin_amdgcn_s_setprio(1);
        #pragma unroll
        for (int g = 0; g < 4; ++g) {
            const _Float16* kp = kb + (size_t)(kbase + kv + g * 16 + lq) * 64 + ls * 8;
            f16x8 kf0 = *(const f16x8*)kp;
            f16x8 kf1 = *(const f16x8*)(kp + 32);
            #pragma unroll
            for (int qg = 0; qg < 2; ++qg) {
                f32x4 z = {};
                z = mfma16(kf0, qf[qg][0], z);
                z = mfma16(kf1, qf[qg][1], z);
                s[qg][g] = z;   // S^T: row = key, col = q = lane&15
            }
        }
        __builtin_amdgcn_s_setprio(0);
        #pragma unroll
        for (int qg = 0; qg < 2; ++qg) {
            float tsum = 0.f;
            #pragma unroll
            for (int g = 0; g < 4; ++g) {
                f16x4 ph;
                #pragma unroll
                for (int r = 0; r < 4; ++r) {
                    float pv = __expf(s[qg][g][r] * 0.125f);
                    tsum += pv;
                    ph[r] = (_Float16)pv;
                }
                int gi = 2 * g + (ls >> 1);   // logical 8-f16 granule of key block
                *(f16x4*)&P[w][qg][lq][(((gi ^ (lq & 7)) << 3) | ((ls & 1) << 2))] = ph;
            }
            tsum += __shfl_xor(tsum, 16, 64);
            tsum += __shfl_xor(tsum, 32, 64);
            lsum[qg] += tsum;
        }
        // ctx^T += V^T @ P^T  (A-frag: vt d-major contiguous; B-frag: swizzled P rows)
        __builtin_amdgcn_s_setprio(1);
        #pragma unroll
        for (int c = 0; c < 2; ++c) {
            f16x8 pf[2];
            #pragma unroll
            for (int qg = 0; qg < 2; ++qg)
                pf[qg] = *(const f16x8*)&P[w][qg][lq][((4 * c + ls) ^ (lq & 7)) << 3];
            #pragma unroll
            for (int dg = 0; dg < 4; ++dg) {
                const _Float16* vp = vb + (size_t)(dg * 16 + lq) * NCTX + kbase + kv + c * 32 + ls * 8;
                f16x8 vf = *(const f16x8*)vp;
                #pragma unroll
                for (int qg = 0; qg < 2; ++qg)
                    acc[qg][dg] = mfma16(vf, pf[qg], acc[qg][dg]);
            }
        }
        __builtin_amdgcn_s_setprio(0);
    }

    // write ctx directly in the pre-split duplicated/swizzled layout
    #pragma unroll
    for (int qg = 0; qg < 2; ++qg) {
        const float inv = 1.f / lsum[qg];
        const int m = q0 + qg * 16 + lq;      // ctx^T col = q = lane&15
        _Float16* rowp = A2o + (size_t)m * 3072;
        #pragma unroll
        for (int dg = 0; dg < 4; ++dg) {
            f16x4 ch, cl;
            #pragma unroll
            for (int r = 0; r < 4; ++r) {
                float v = acc[qg][dg][r] * inv;
                _Float16 hh = (_Float16)v;
                ch[r] = hh; cl[r] = (_Float16)(v - (float)hh);
            }
            int g = 2 * dg + (ls >> 1);
            int c0 = (h << 6) | ((g ^ (m & 7)) << 3) | ((ls & 1) << 2);
            *(f16x4*)(rowp + c0)        = ch;
            *(f16x4*)(rowp + 1024 + c0) = ch;
            *(f16x4*)(rowp + 2048 + c0) = cl;
        }
    }
}

extern "C" void kernel_launch(void* const* d_in, const int* in_sizes, int n_in,
                              void* d_out, int out_size, void* d_ws, size_t ws_size,
                              hipStream_t stream)
{
    const float* x  = (const float*)d_in[0];
    const float* Wq = (const float*)d_in[1];
    const float* bq = (const float*)d_in[2];
    const float* Wk = (const float*)d_in[3];
    const float* Wv = (const float*)d_in[4];
    const float* bv = (const float*)d_in[5];
    const float* Wo = (const float*)d_in[6];
    const float* bo = (const float*)d_in[7];
    float* out = (float*)d_out;

    char* p = (char*)d_ws;
    _Float16* A2x = (_Float16*)p; p += (size_t)MPAD * 3072 * 2;
    _Float16* W2  = (_Float16*)p; p += (size_t)4096 * 3072 * 2;
    _Float16* qh  = (_Float16*)p; p += (size_t)NHEAD * NCTX * 64 * 2;
    _Float16* kh  = (_Float16*)p; p += (size_t)NHEAD * NCTX * 64 * 2;
    _Float16* vt  = (_Float16*)p; p += (size_t)NHEAD * NCTX * 64 * 2;
    _Float16* A2o = (_Float16*)p; p += (size_t)MPAD * 3072 * 2;

    presplit_A<<<dim3(MPAD * 128 / 256), 256, 0, stream>>>(x, A2x);
    presplit_W<<<dim3(4096 * 128 / 256), 256, 0, stream>>>(Wq, Wk, Wv, Wo, W2);
    gemm8<0><<<dim3(24 * 32), 512, 0, stream>>>(A2x, W2, bq, bv, nullptr,
                                                qh, kh, vt, nullptr);
    attn_kernel<<<dim3(48 * 16), 256, 0, stream>>>(qh, kh, vt, A2o);
    gemm8<1><<<dim3(24 * 8), 512, 0, stream>>>(A2o, W2, nullptr, nullptr, bo,
                                               nullptr, nullptr, nullptr, out);
}

// Round 4
// 257.258 us; speedup vs baseline: 1.6030x; 1.3968x over previous
//
#include <hip/hip_runtime.h>
#include <hip/hip_fp16.h>
#include <stdint.h>

#define NCTX 5952
#define NHEAD 16

typedef _Float16 f16x8 __attribute__((ext_vector_type(8)));
typedef _Float16 f16x4 __attribute__((ext_vector_type(4)));
typedef float    f32x4 __attribute__((ext_vector_type(4)));

typedef const __attribute__((address_space(1))) void* gp1;
typedef __attribute__((address_space(3))) void* lp3;

__device__ __forceinline__ f32x4 mfma16(f16x8 a, f16x8 b, f32x4 c) {
    return __builtin_amdgcn_mfma_f32_16x16x32_f16(a, b, c, 0, 0, 0);
}

#define SBAR() do { __builtin_amdgcn_sched_barrier(0); \
                    __builtin_amdgcn_s_barrier();      \
                    __builtin_amdgcn_sched_barrier(0); } while (0)

// per-seq tables: lengths {512,576,640,704,768,832,896,1024}
__device__ const int kQT[9]    = {0, 4, 9, 14, 20, 26, 33, 40, 48}; // cum 128-row q-tiles
__device__ const int kBASE8[8] = {0, 512, 1088, 1728, 2432, 3200, 4032, 4928};
__device__ const int kLEN[8]   = {512, 576, 640, 704, 768, 832, 896, 1024};

// ---- pre-split: fp32 -> f16 hi/lo, four PLAIN row-major arrays (no dup, no swizzle;
// the GEMM applies the LDS swizzle via its global source addresses) ----
__global__ __launch_bounds__(256) void presplit_A(const float* __restrict__ x,
                                                  _Float16* __restrict__ Ah,
                                                  _Float16* __restrict__ Al) {
    int idx = blockIdx.x * 256 + threadIdx.x;      // NCTX * 128
    int m = idx >> 7, k8 = (idx & 127) << 3;
    const float* xp = x + (size_t)m * 1024 + k8;
    f16x8 hi, lo;
    #pragma unroll
    for (int e = 0; e < 8; ++e) {
        float v = xp[e];
        _Float16 h = (_Float16)v;
        hi[e] = h; lo[e] = (_Float16)(v - (float)h);
    }
    *(f16x8*)&Ah[(size_t)m * 1024 + k8] = hi;
    *(f16x8*)&Al[(size_t)m * 1024 + k8] = lo;
}

__global__ __launch_bounds__(256) void presplit_W(
    const float* __restrict__ Wq, const float* __restrict__ Wk,
    const float* __restrict__ Wv, const float* __restrict__ Wo,
    _Float16* __restrict__ Wh, _Float16* __restrict__ Wl) {
    int idx = blockIdx.x * 256 + threadIdx.x;      // 4096 * 128
    int n = idx >> 7, k8 = (idx & 127) << 3;
    const float* src = (n < 1024) ? Wq : (n < 2048) ? Wk : (n < 3072) ? Wv : Wo;
    const float* xp = src + (size_t)(n & 1023) * 1024 + k8;
    f16x8 hi, lo;
    #pragma unroll
    for (int e = 0; e < 8; ++e) {
        float v = xp[e];
        _Float16 h = (_Float16)v;
        hi[e] = h; lo[e] = (_Float16)(v - (float)h);
    }
    *(f16x8*)&Wh[(size_t)n * 1024 + k8] = hi;
    *(f16x8*)&Wl[(size_t)n * 1024 + k8] = lo;
}

// ---- 3-pairing split GEMM: C = Ah*Bh + Ah*Bl + Al*Bh, K=1024, BK=32 ----
// BM=192; MODE 0: BN=192, grid 31x16=496, q/k/v epilogue
//         MODE 1: BN=128, grid 31x8 =248, fp32 out + bo
// 3 LDS buffers, counted vmcnt, 3 phases/K-step (18 or 12 MFMA each), 8 waves.
template <int MODE>
__global__ __launch_bounds__(512) void gemm3p(
    const _Float16* __restrict__ Ahg, const _Float16* __restrict__ Alg,
    const _Float16* __restrict__ Whg, const _Float16* __restrict__ Wlg,
    const float* __restrict__ bq, const float* __restrict__ bv, const float* __restrict__ bo,
    _Float16* __restrict__ qh, _Float16* __restrict__ kh, _Float16* __restrict__ vt,
    float* __restrict__ outp)
{
    constexpr int BM   = 192;
    constexpr int BN   = (MODE == 0) ? 192 : 128;
    constexpr int MI   = 6;                 // m-frags/wave (96 rows)
    constexpr int NF   = BN / 64;           // n-frags/wave (BN/4 cols)
    constexpr int NTg  = (MODE == 0) ? 16 : 8;
    constexpr int nA   = 12;                // 16-row stage blocks per A array
    constexpr int nB   = BN / 16;
    constexpr int SPW  = (2 * nA + 2 * nB) / 8;   // stage instrs per wave: 6 / 5
    constexpr int ABYT = BM * 64;           // 12288 B per A array per buf
    constexpr int BBYT = BN * 64;
    constexpr int BUF  = 2 * ABYT + 2 * BBYT;     // 49152 / 40960
    constexpr int T    = 32;                // K-steps
    constexpr int W0   = (MODE == 0) ? 0 : 3072;

    __shared__ __align__(16) char lds[3 * BUF];

    int bid = blockIdx.x;
    constexpr int cpx = (31 * NTg) / 8;
    bid = (bid & 7) * cpx + (bid >> 3);     // bijective XCD swizzle
    const int mt = bid / NTg, nt = bid % NTg;
    const int m0 = mt * BM, n0 = nt * BN;
    const int tid = threadIdx.x;
    const int w = tid >> 6, l = tid & 63;
    const int ls = l >> 4, lq = l & 15;
    const int wm = w >> 2, wn = w & 3;

    // stage sources: lane fetches logical granule (j ^ ((row>>1)&3)) so the LDS
    // tile ends up granule-swizzled while the DMA dest stays linear (rule 21).
    const char* gsrc[SPW];
    int         ldst[SPW];
    #pragma unroll
    for (int s = 0; s < SPW; ++s) {
        int f = w * SPW + s;
        const _Float16* base; int row; int aoff;
        if (f < nA)               { base = Ahg; row = m0 + f * 16;                 aoff = f * 1024; }
        else if (f < 2 * nA)      { base = Alg; row = m0 + (f - nA) * 16;          aoff = ABYT + (f - nA) * 1024; }
        else if (f < 2 * nA + nB) { base = Whg; row = W0 + n0 + (f - 2 * nA) * 16; aoff = 2 * ABYT + (f - 2 * nA) * 1024; }
        else                      { base = Wlg; row = W0 + n0 + (f - 2 * nA - nB) * 16;
                                    aoff = 2 * ABYT + BBYT + (f - 2 * nA - nB) * 1024; }
        row += (l >> 2);
        gsrc[s] = (const char*)base + (size_t)row * 2048 + 16 * ((l & 3) ^ ((row >> 1) & 3));
        ldst[s] = aoff;
    }
    auto STG = [&](int buf, int t2, int s) {
        __builtin_amdgcn_global_load_lds((gp1)(gsrc[s] + (size_t)t2 * 64),
                                         (lp3)(lds + buf * BUF + ldst[s]), 16, 0, 0);
    };

    // fragment LDS offsets (lane-constant); storage granule = ls ^ ((row>>1)&3)
    int aoA[MI], aoB[NF];
    #pragma unroll
    for (int i = 0; i < MI; ++i) {
        int r = wm * 96 + i * 16 + lq;
        aoA[i] = r * 64 + 16 * (ls ^ ((r >> 1) & 3));
    }
    #pragma unroll
    for (int j = 0; j < NF; ++j) {
        int r = wn * (BN / 4) + j * 16 + lq;
        aoB[j] = 2 * ABYT + r * 64 + 16 * (ls ^ ((r >> 1) & 3));
    }

    f32x4 acc[MI][NF] = {};

    // prologue: stage tiles 0,1 into bufs 0,1; drain tile0, keep tile1 in flight
    #pragma unroll
    for (int pt = 0; pt < 2; ++pt)
        #pragma unroll
        for (int s = 0; s < SPW; ++s) STG(pt, pt, s);
    if constexpr (SPW == 6) asm volatile("s_waitcnt vmcnt(6)" ::: "memory");
    else                    asm volatile("s_waitcnt vmcnt(5)" ::: "memory");
    SBAR();

    int cb = 0, pb = 2;
    #pragma unroll 1
    for (int t = 0; t < T; ++t) {
        const bool pf = (t + 2 < T);
        const char* cbp = lds + cb * BUF;
        f16x8 ah[MI], bh[NF], bl[NF], al[MI];
        // ---- P0: Ah*Bh ----
        #pragma unroll
        for (int i = 0; i < MI; ++i) ah[i] = *(const f16x8*)(cbp + aoA[i]);
        #pragma unroll
        for (int j = 0; j < NF; ++j) bh[j] = *(const f16x8*)(cbp + aoB[j]);
        if (pf) { STG(pb, t + 2, 0); STG(pb, t + 2, 1); }
        SBAR();
        __builtin_amdgcn_s_setprio(1);
        #pragma unroll
        for (int i = 0; i < MI; ++i)
            #pragma unroll
            for (int j = 0; j < NF; ++j)
                acc[i][j] = mfma16(ah[i], bh[j], acc[i][j]);
        __builtin_amdgcn_s_setprio(0);
        SBAR();
        // ---- P1: Ah*Bl ----
        #pragma unroll
        for (int j = 0; j < NF; ++j) bl[j] = *(const f16x8*)(cbp + aoB[j] + BBYT);
        if (pf) { STG(pb, t + 2, 2); STG(pb, t + 2, 3); }
        SBAR();
        __builtin_amdgcn_s_setprio(1);
        #pragma unroll
        for (int i = 0; i < MI; ++i)
            #pragma unroll
            for (int j = 0; j < NF; ++j)
                acc[i][j] = mfma16(ah[i], bl[j], acc[i][j]);
        __builtin_amdgcn_s_setprio(0);
        SBAR();
        // ---- P2: Al*Bh ----
        #pragma unroll
        for (int i = 0; i < MI; ++i) al[i] = *(const f16x8*)(cbp + aoA[i] + ABYT);
        if (pf) { STG(pb, t + 2, 4); if constexpr (SPW == 6) STG(pb, t + 2, 5); }
        SBAR();
        __builtin_amdgcn_s_setprio(1);
        #pragma unroll
        for (int i = 0; i < MI; ++i)
            #pragma unroll
            for (int j = 0; j < NF; ++j)
                acc[i][j] = mfma16(al[i], bh[j], acc[i][j]);
        __builtin_amdgcn_s_setprio(0);
        if (pf) {
            if constexpr (SPW == 6) asm volatile("s_waitcnt vmcnt(6)" ::: "memory");
            else                    asm volatile("s_waitcnt vmcnt(5)" ::: "memory");
        } else {
            asm volatile("s_waitcnt vmcnt(0)" ::: "memory");
        }
        SBAR();
        cb = (cb == 2) ? 0 : cb + 1;
        pb = (pb == 2) ? 0 : pb + 1;
    }

    // C/D layout: col = lane&15 (-> n), row = (lane>>4)*4 + reg (-> m)
    #pragma unroll
    for (int i = 0; i < MI; ++i)
        #pragma unroll
        for (int j = 0; j < NF; ++j) {
            const int mb = m0 + wm * 96 + i * 16 + 4 * ls;
            const int n  = n0 + wn * (BN / 4) + j * 16 + lq;
            if (MODE == 0) {
                const int which = n >> 10, nn = n & 1023;
                const int hh = nn >> 6, dd = nn & 63;
                if (which == 2) {
                    f16x4 vv;
                    #pragma unroll
                    for (int r = 0; r < 4; ++r) vv[r] = (_Float16)(acc[i][j][r] + bv[nn]);
                    *(f16x4*)&vt[((size_t)hh * 64 + dd) * NCTX + mb] = vv;   // d-major
                } else if (which == 0) {
                    #pragma unroll
                    for (int r = 0; r < 4; ++r)
                        qh[((size_t)hh * NCTX + mb + r) * 64 + dd] = (_Float16)(acc[i][j][r] + bq[nn]);
                } else {
                    #pragma unroll
                    for (int r = 0; r < 4; ++r)
                        kh[((size_t)hh * NCTX + mb + r) * 64 + dd] = (_Float16)acc[i][j][r];
                }
            } else {
                #pragma unroll
                for (int r = 0; r < 4; ++r)
                    outp[(size_t)(mb + r) * 1024 + n] = acc[i][j][r] + bo[n];
            }
        }
}

// ---- flash attention (no-max), 4 waves x 32 q-rows per 128-row tile ----
__global__ __launch_bounds__(256) void attn_kernel(
    const _Float16* __restrict__ qh, const _Float16* __restrict__ kh,
    const _Float16* __restrict__ vt,
    _Float16* __restrict__ Ahc, _Float16* __restrict__ Alc)
{
    __shared__ alignas(16) _Float16 P[4][2][16][64];
    const int bid = blockIdx.x;
    const int h = bid & 15, t = bid >> 4;
    int b = 0;
    while (t >= kQT[b + 1]) ++b;
    const int kbase = kBASE8[b];
    const int L = kLEN[b];
    const int w = threadIdx.x >> 6, l = threadIdx.x & 63;
    const int ls = l >> 4, lq = l & 15;
    const int q0l = (t - kQT[b]) * 128 + w * 32;
    if (q0l >= L) return;          // tail waves of ragged tiles; no barriers below
    const int q0 = kbase + q0l;

    f16x8 qf[2][2];
    #pragma unroll
    for (int qg = 0; qg < 2; ++qg) {
        const _Float16* qp = qh + ((size_t)h * NCTX + q0 + qg * 16 + lq) * 64 + ls * 8;
        qf[qg][0] = *(const f16x8*)qp;
        qf[qg][1] = *(const f16x8*)(qp + 32);
    }
    const _Float16* kb = kh + (size_t)h * NCTX * 64;
    const _Float16* vb = vt + (size_t)h * 64 * NCTX;

    f32x4 acc[2][4] = {};
    float lsum[2] = {0.f, 0.f};

    for (int kv = 0; kv < L; kv += 64) {
        f32x4 s[2][4];
        __builtin_amdgcn_s_setprio(1);
        #pragma unroll
        for (int g = 0; g < 4; ++g) {
            const _Float16* kp = kb + (size_t)(kbase + kv + g * 16 + lq) * 64 + ls * 8;
            f16x8 kf0 = *(const f16x8*)kp;
            f16x8 kf1 = *(const f16x8*)(kp + 32);
            #pragma unroll
            for (int qg = 0; qg < 2; ++qg) {
                f32x4 z = {};
                z = mfma16(kf0, qf[qg][0], z);
                z = mfma16(kf1, qf[qg][1], z);
                s[qg][g] = z;   // S^T: row = key, col = q = lane&15
            }
        }
        __builtin_amdgcn_s_setprio(0);
        #pragma unroll
        for (int qg = 0; qg < 2; ++qg) {
            float tsum = 0.f;
            #pragma unroll
            for (int g = 0; g < 4; ++g) {
                f16x4 ph;
                #pragma unroll
                for (int r = 0; r < 4; ++r) {
                    float pv = __expf(s[qg][g][r] * 0.125f);
                    tsum += pv;
                    ph[r] = (_Float16)pv;
                }
                int gi = 2 * g + (ls >> 1);   // logical 8-f16 granule of key block
                *(f16x4*)&P[w][qg][lq][(((gi ^ (lq & 7)) << 3) | ((ls & 1) << 2))] = ph;
            }
            tsum += __shfl_xor(tsum, 16, 64);
            tsum += __shfl_xor(tsum, 32, 64);
            lsum[qg] += tsum;
        }
        // ctx^T += V^T @ P^T  (A-frag: vt d-major contiguous; B-frag: swizzled P rows)
        __builtin_amdgcn_s_setprio(1);
        #pragma unroll
        for (int c = 0; c < 2; ++c) {
            f16x8 pf[2];
            #pragma unroll
            for (int qg = 0; qg < 2; ++qg)
                pf[qg] = *(const f16x8*)&P[w][qg][lq][((4 * c + ls) ^ (lq & 7)) << 3];
            #pragma unroll
            for (int dg = 0; dg < 4; ++dg) {
                const _Float16* vp = vb + (size_t)(dg * 16 + lq) * NCTX + kbase + kv + c * 32 + ls * 8;
                f16x8 vf = *(const f16x8*)vp;
                #pragma unroll
                for (int qg = 0; qg < 2; ++qg)
                    acc[qg][dg] = mfma16(vf, pf[qg], acc[qg][dg]);
            }
        }
        __builtin_amdgcn_s_setprio(0);
    }

    // epilogue: hi/lo split of ctx into plain arrays (GEMM swizzles on read)
    #pragma unroll
    for (int qg = 0; qg < 2; ++qg) {
        const float inv = 1.f / lsum[qg];
        const int m = q0 + qg * 16 + lq;      // ctx^T col = q = lane&15
        _Float16* rh = Ahc + (size_t)m * 1024 + h * 64;
        _Float16* rl = Alc + (size_t)m * 1024 + h * 64;
        #pragma unroll
        for (int dg = 0; dg < 4; ++dg) {
            f16x4 ch, cl;
            #pragma unroll
            for (int r = 0; r < 4; ++r) {
                float v = acc[qg][dg][r] * inv;
                _Float16 hh = (_Float16)v;
                ch[r] = hh; cl[r] = (_Float16)(v - (float)hh);
            }
            *(f16x4*)(rh + dg * 16 + 4 * ls) = ch;
            *(f16x4*)(rl + dg * 16 + 4 * ls) = cl;
        }
    }
}

extern "C" void kernel_launch(void* const* d_in, const int* in_sizes, int n_in,
                              void* d_out, int out_size, void* d_ws, size_t ws_size,
                              hipStream_t stream)
{
    const float* x  = (const float*)d_in[0];
    const float* Wq = (const float*)d_in[1];
    const float* bq = (const float*)d_in[2];
    const float* Wk = (const float*)d_in[3];
    const float* Wv = (const float*)d_in[4];
    const float* bv = (const float*)d_in[5];
    const float* Wo = (const float*)d_in[6];
    const float* bo = (const float*)d_in[7];
    float* out = (float*)d_out;

    char* p = (char*)d_ws;
    _Float16* Ah  = (_Float16*)p; p += (size_t)NCTX * 1024 * 2;
    _Float16* Al  = (_Float16*)p; p += (size_t)NCTX * 1024 * 2;
    _Float16* Wh  = (_Float16*)p; p += (size_t)4096 * 1024 * 2;
    _Float16* Wl  = (_Float16*)p; p += (size_t)4096 * 1024 * 2;
    _Float16* qh  = (_Float16*)p; p += (size_t)NHEAD * NCTX * 64 * 2;
    _Float16* kh  = (_Float16*)p; p += (size_t)NHEAD * NCTX * 64 * 2;
    _Float16* vt  = (_Float16*)p; p += (size_t)NHEAD * NCTX * 64 * 2;
    _Float16* Ahc = (_Float16*)p; p += (size_t)NCTX * 1024 * 2;
    _Float16* Alc = (_Float16*)p; p += (size_t)NCTX * 1024 * 2;
    // total ~94 MiB

    presplit_A<<<dim3(NCTX * 128 / 256), 256, 0, stream>>>(x, Ah, Al);
    presplit_W<<<dim3(4096 * 128 / 256), 256, 0, stream>>>(Wq, Wk, Wv, Wo, Wh, Wl);
    gemm3p<0><<<dim3(31 * 16), 512, 0, stream>>>(Ah, Al, Wh, Wl, bq, bv, nullptr,
                                                 qh, kh, vt, nullptr);
    attn_kernel<<<dim3(48 * 16), 256, 0, stream>>>(qh, kh, vt, Ahc, Alc);
    gemm3p<1><<<dim3(31 * 8), 512, 0, stream>>>(Ahc, Alc, Wh, Wl, nullptr, nullptr, bo,
                                                nullptr, nullptr, nullptr, out);
}

// Round 5
// 250.831 us; speedup vs baseline: 1.6441x; 1.0256x over previous
//
#include <hip/hip_runtime.h>
#include <hip/hip_fp16.h>
#include <stdint.h>

#define NCTX 5952
#define NHEAD 16

typedef _Float16 f16x8 __attribute__((ext_vector_type(8)));
typedef _Float16 f16x4 __attribute__((ext_vector_type(4)));
typedef float    f32x4 __attribute__((ext_vector_type(4)));

typedef const __attribute__((address_space(1))) void* gp1;
typedef __attribute__((address_space(3))) void* lp3;

__device__ __forceinline__ f32x4 mfma16(f16x8 a, f16x8 b, f32x4 c) {
    return __builtin_amdgcn_mfma_f32_16x16x32_f16(a, b, c, 0, 0, 0);
}

// per-seq tables: lengths {512,576,640,704,768,832,896,1024}
__device__ const int kQT[9]    = {0, 4, 9, 14, 20, 26, 33, 40, 48}; // cum 128-row q-tiles
__device__ const int kBASE8[8] = {0, 512, 1088, 1728, 2432, 3200, 4032, 4928};
__device__ const int kLEN[8]   = {512, 576, 640, 704, 768, 832, 896, 1024};

// ---- fused pre-split: fp32 -> f16 hi/lo plain row-major arrays ----
// blocks [0, 2976): x -> Ah/Al ; blocks [2976, 5024): Wq|Wk|Wv|Wo -> Wh/Wl
__global__ __launch_bounds__(256) void presplit_all(
    const float* __restrict__ x,
    const float* __restrict__ Wq, const float* __restrict__ Wk,
    const float* __restrict__ Wv, const float* __restrict__ Wo,
    _Float16* __restrict__ Ah, _Float16* __restrict__ Al,
    _Float16* __restrict__ Wh, _Float16* __restrict__ Wl)
{
    constexpr int NA = NCTX * 128 / 256;   // 2976
    const int bid = blockIdx.x;
    const float* src;
    _Float16 *dh, *dl;
    size_t off;
    if (bid < NA) {
        int idx = bid * 256 + threadIdx.x;
        int m = idx >> 7, k8 = (idx & 127) << 3;
        src = x + (size_t)m * 1024 + k8;
        off = (size_t)m * 1024 + k8;
        dh = Ah; dl = Al;
    } else {
        int idx = (bid - NA) * 256 + threadIdx.x;
        int n = idx >> 7, k8 = (idx & 127) << 3;
        const float* s = (n < 1024) ? Wq : (n < 2048) ? Wk : (n < 3072) ? Wv : Wo;
        src = s + (size_t)(n & 1023) * 1024 + k8;
        off = (size_t)n * 1024 + k8;
        dh = Wh; dl = Wl;
    }
    f16x8 hi, lo;
    #pragma unroll
    for (int e = 0; e < 8; ++e) {
        float v = src[e];
        _Float16 h = (_Float16)v;
        hi[e] = h; lo[e] = (_Float16)(v - (float)h);
    }
    *(f16x8*)&dh[off] = hi;
    *(f16x8*)&dl[off] = lo;
}

// ---- 3-pairing split GEMM: C = Ah*Bh + Ah*Bl + Al*Bh, K=1024, BK=32 ----
// BM=192; MODE 0: BN=192, grid 31x16=496, q/k/v epilogue
//         MODE 1: BN=128, grid 31x8 =248, fp32 out + bo
// 3 LDS buffers; ONE barrier + counted vmcnt per K-step; compiler-scheduled interior.
template <int MODE>
__global__ __launch_bounds__(512) void gemm3p(
    const _Float16* __restrict__ Ahg, const _Float16* __restrict__ Alg,
    const _Float16* __restrict__ Whg, const _Float16* __restrict__ Wlg,
    const float* __restrict__ bq, const float* __restrict__ bv, const float* __restrict__ bo,
    _Float16* __restrict__ qh, _Float16* __restrict__ kh, _Float16* __restrict__ vt,
    float* __restrict__ outp)
{
    constexpr int BM   = 192;
    constexpr int BN   = (MODE == 0) ? 192 : 128;
    constexpr int MI   = 6;                 // m-frags/wave (96 rows)
    constexpr int NF   = BN / 64;           // n-frags/wave
    constexpr int NTg  = (MODE == 0) ? 16 : 8;
    constexpr int nA   = 12;                // 16-row stage blocks per A array
    constexpr int nB   = BN / 16;
    constexpr int SPW  = (2 * nA + 2 * nB) / 8;   // stage instrs per wave: 6 / 5
    constexpr int ABYT = BM * 64;           // bytes per A array per buf
    constexpr int BBYT = BN * 64;
    constexpr int BUF  = 2 * ABYT + 2 * BBYT;
    constexpr int T    = 32;                // K-steps
    constexpr int W0   = (MODE == 0) ? 0 : 3072;

    __shared__ __align__(16) char lds[3 * BUF];

    int bid = blockIdx.x;
    constexpr int cpx = (31 * NTg) / 8;
    bid = (bid & 7) * cpx + (bid >> 3);     // bijective XCD swizzle
    const int mt = bid / NTg, nt = bid % NTg;
    const int m0 = mt * BM, n0 = nt * BN;
    const int tid = threadIdx.x;
    const int w = tid >> 6, l = tid & 63;
    const int ls = l >> 4, lq = l & 15;
    const int wm = w >> 2, wn = w & 3;

    // stage sources: lane fetches logical granule (j ^ ((row>>1)&3)) so the LDS
    // tile ends up granule-swizzled while the DMA dest stays linear (rule 21).
    const char* gsrc[SPW];
    int         ldst[SPW];
    #pragma unroll
    for (int s = 0; s < SPW; ++s) {
        int f = w * SPW + s;
        const _Float16* base; int row; int aoff;
        if (f < nA)               { base = Ahg; row = m0 + f * 16;                 aoff = f * 1024; }
        else if (f < 2 * nA)      { base = Alg; row = m0 + (f - nA) * 16;          aoff = ABYT + (f - nA) * 1024; }
        else if (f < 2 * nA + nB) { base = Whg; row = W0 + n0 + (f - 2 * nA) * 16; aoff = 2 * ABYT + (f - 2 * nA) * 1024; }
        else                      { base = Wlg; row = W0 + n0 + (f - 2 * nA - nB) * 16;
                                    aoff = 2 * ABYT + BBYT + (f - 2 * nA - nB) * 1024; }
        row += (l >> 2);
        gsrc[s] = (const char*)base + (size_t)row * 2048 + 16 * ((l & 3) ^ ((row >> 1) & 3));
        ldst[s] = aoff;
    }
    auto STG = [&](int buf, int t2, int s) {
        __builtin_amdgcn_global_load_lds((gp1)(gsrc[s] + (size_t)t2 * 64),
                                         (lp3)(lds + buf * BUF + ldst[s]), 16, 0, 0);
    };

    // fragment LDS offsets (lane-constant); storage granule = ls ^ ((row>>1)&3)
    int aoA[MI], aoB[NF];
    #pragma unroll
    for (int i = 0; i < MI; ++i) {
        int r = wm * 96 + i * 16 + lq;
        aoA[i] = r * 64 + 16 * (ls ^ ((r >> 1) & 3));
    }
    #pragma unroll
    for (int j = 0; j < NF; ++j) {
        int r = wn * (BN / 4) + j * 16 + lq;
        aoB[j] = 2 * ABYT + r * 64 + 16 * (ls ^ ((r >> 1) & 3));
    }

    f32x4 acc[MI][NF] = {};

    // prologue: stage tiles 0,1 into bufs 0,1; drain tile0, keep tile1 in flight
    #pragma unroll
    for (int pt = 0; pt < 2; ++pt)
        #pragma unroll
        for (int s = 0; s < SPW; ++s) STG(pt, pt, s);
    if constexpr (SPW == 6) asm volatile("s_waitcnt vmcnt(6)" ::: "memory");
    else                    asm volatile("s_waitcnt vmcnt(5)" ::: "memory");
    __builtin_amdgcn_s_barrier();

    int cb = 0, pb = 2;
    #pragma unroll 1
    for (int t = 0; t < T; ++t) {
        const bool pf = (t + 2 < T);
        const char* cbp = lds + cb * BUF;
        // issue next-next tile's DMA early (targets pb: not read this step or next)
        if (pf)
            #pragma unroll
            for (int s = 0; s < SPW; ++s) STG(pb, t + 2, s);
        // straight-line reads + MFMAs: compiler interleaves with fine lgkmcnt
        f16x8 ah[MI], al[MI], bh[NF], bl[NF];
        #pragma unroll
        for (int i = 0; i < MI; ++i) ah[i] = *(const f16x8*)(cbp + aoA[i]);
        #pragma unroll
        for (int j = 0; j < NF; ++j) bh[j] = *(const f16x8*)(cbp + aoB[j]);
        #pragma unroll
        for (int j = 0; j < NF; ++j) bl[j] = *(const f16x8*)(cbp + aoB[j] + BBYT);
        #pragma unroll
        for (int i = 0; i < MI; ++i) al[i] = *(const f16x8*)(cbp + aoA[i] + ABYT);
        #pragma unroll
        for (int i = 0; i < MI; ++i)
            #pragma unroll
            for (int j = 0; j < NF; ++j)
                acc[i][j] = mfma16(ah[i], bh[j], acc[i][j]);
        #pragma unroll
        for (int i = 0; i < MI; ++i)
            #pragma unroll
            for (int j = 0; j < NF; ++j)
                acc[i][j] = mfma16(ah[i], bl[j], acc[i][j]);
        #pragma unroll
        for (int i = 0; i < MI; ++i)
            #pragma unroll
            for (int j = 0; j < NF; ++j)
                acc[i][j] = mfma16(al[i], bh[j], acc[i][j]);
        // one sync point per K-step: my reads done (lgkm), tile t+1 resident (vmcnt)
        if (pf) {
            if constexpr (SPW == 6) asm volatile("s_waitcnt vmcnt(6) lgkmcnt(0)" ::: "memory");
            else                    asm volatile("s_waitcnt vmcnt(5) lgkmcnt(0)" ::: "memory");
        } else {
            asm volatile("s_waitcnt vmcnt(0) lgkmcnt(0)" ::: "memory");
        }
        __builtin_amdgcn_s_barrier();
        cb = (cb == 2) ? 0 : cb + 1;
        pb = (pb == 2) ? 0 : pb + 1;
    }

    // C/D layout: col = lane&15 (-> n), row = (lane>>4)*4 + reg (-> m)
    #pragma unroll
    for (int i = 0; i < MI; ++i)
        #pragma unroll
        for (int j = 0; j < NF; ++j) {
            const int mb = m0 + wm * 96 + i * 16 + 4 * ls;
            const int n  = n0 + wn * (BN / 4) + j * 16 + lq;
            if (MODE == 0) {
                const int which = n >> 10, nn = n & 1023;
                const int hh = nn >> 6, dd = nn & 63;
                if (which == 2) {
                    f16x4 vv;
                    #pragma unroll
                    for (int r = 0; r < 4; ++r) vv[r] = (_Float16)(acc[i][j][r] + bv[nn]);
                    *(f16x4*)&vt[((size_t)hh * 64 + dd) * NCTX + mb] = vv;   // d-major
                } else if (which == 0) {
                    #pragma unroll
                    for (int r = 0; r < 4; ++r)
                        qh[((size_t)hh * NCTX + mb + r) * 64 + dd] = (_Float16)(acc[i][j][r] + bq[nn]);
                } else {
                    #pragma unroll
                    for (int r = 0; r < 4; ++r)
                        kh[((size_t)hh * NCTX + mb + r) * 64 + dd] = (_Float16)acc[i][j][r];
                }
            } else {
                #pragma unroll
                for (int r = 0; r < 4; ++r)
                    outp[(size_t)(mb + r) * 1024 + n] = acc[i][j][r] + bo[n];
            }
        }
}

// ---- flash attention (no-max), 4 waves x 32 q-rows per 128-row tile ----
__global__ __launch_bounds__(256) void attn_kernel(
    const _Float16* __restrict__ qh, const _Float16* __restrict__ kh,
    const _Float16* __restrict__ vt,
    _Float16* __restrict__ Ahc, _Float16* __restrict__ Alc)
{
    __shared__ alignas(16) _Float16 P[4][2][16][64];
    const int bid = blockIdx.x;
    const int h = bid & 15, t = bid >> 4;
    int b = 0;
    while (t >= kQT[b + 1]) ++b;
    const int kbase = kBASE8[b];
    const int L = kLEN[b];
    const int w = threadIdx.x >> 6, l = threadIdx.x & 63;
    const int ls = l >> 4, lq = l & 15;
    const int q0l = (t - kQT[b]) * 128 + w * 32;
    if (q0l >= L) return;          // tail waves of ragged tiles; no barriers below
    const int q0 = kbase + q0l;

    f16x8 qf[2][2];
    #pragma unroll
    for (int qg = 0; qg < 2; ++qg) {
        const _Float16* qp = qh + ((size_t)h * NCTX + q0 + qg * 16 + lq) * 64 + ls * 8;
        qf[qg][0] = *(const f16x8*)qp;
        qf[qg][1] = *(const f16x8*)(qp + 32);
    }
    const _Float16* kb = kh + (size_t)h * NCTX * 64;
    const _Float16* vb = vt + (size_t)h * 64 * NCTX;

    f32x4 acc[2][4] = {};
    float lsum[2] = {0.f, 0.f};

    for (int kv = 0; kv < L; kv += 64) {
        f32x4 s[2][4];
        __builtin_amdgcn_s_setprio(1);
        #pragma unroll
        for (int g = 0; g < 4; ++g) {
            const _Float16* kp = kb + (size_t)(kbase + kv + g * 16 + lq) * 64 + ls * 8;
            f16x8 kf0 = *(const f16x8*)kp;
            f16x8 kf1 = *(const f16x8*)(kp + 32);
            #pragma unroll
            for (int qg = 0; qg < 2; ++qg) {
                f32x4 z = {};
                z = mfma16(kf0, qf[qg][0], z);
                z = mfma16(kf1, qf[qg][1], z);
                s[qg][g] = z;   // S^T: row = key, col = q = lane&15
            }
        }
        __builtin_amdgcn_s_setprio(0);
        #pragma unroll
        for (int qg = 0; qg < 2; ++qg) {
            float tsum = 0.f;
            #pragma unroll
            for (int g = 0; g < 4; ++g) {
                f16x4 ph;
                #pragma unroll
                for (int r = 0; r < 4; ++r) {
                    float pv = __expf(s[qg][g][r] * 0.125f);
                    tsum += pv;
                    ph[r] = (_Float16)pv;
                }
                int gi = 2 * g + (ls >> 1);   // logical 8-f16 granule of key block
                *(f16x4*)&P[w][qg][lq][(((gi ^ (lq & 7)) << 3) | ((ls & 1) << 2))] = ph;
            }
            tsum += __shfl_xor(tsum, 16, 64);
            tsum += __shfl_xor(tsum, 32, 64);
            lsum[qg] += tsum;
        }
        // ctx^T += V^T @ P^T  (A-frag: vt d-major contiguous; B-frag: swizzled P rows)
        __builtin_amdgcn_s_setprio(1);
        #pragma unroll
        for (int c = 0; c < 2; ++c) {
            f16x8 pf[2];
            #pragma unroll
            for (int qg = 0; qg < 2; ++qg)
                pf[qg] = *(const f16x8*)&P[w][qg][lq][((4 * c + ls) ^ (lq & 7)) << 3];
            #pragma unroll
            for (int dg = 0; dg < 4; ++dg) {
                const _Float16* vp = vb + (size_t)(dg * 16 + lq) * NCTX + kbase + kv + c * 32 + ls * 8;
                f16x8 vf = *(const f16x8*)vp;
                #pragma unroll
                for (int qg = 0; qg < 2; ++qg)
                    acc[qg][dg] = mfma16(vf, pf[qg], acc[qg][dg]);
            }
        }
        __builtin_amdgcn_s_setprio(0);
    }

    // epilogue: hi/lo split of ctx into plain arrays (GEMM swizzles on read)
    #pragma unroll
    for (int qg = 0; qg < 2; ++qg) {
        const float inv = 1.f / lsum[qg];
        const int m = q0 + qg * 16 + lq;      // ctx^T col = q = lane&15
        _Float16* rh = Ahc + (size_t)m * 1024 + h * 64;
        _Float16* rl = Alc + (size_t)m * 1024 + h * 64;
        #pragma unroll
        for (int dg = 0; dg < 4; ++dg) {
            f16x4 ch, cl;
            #pragma unroll
            for (int r = 0; r < 4; ++r) {
                float v = acc[qg][dg][r] * inv;
                _Float16 hh = (_Float16)v;
                ch[r] = hh; cl[r] = (_Float16)(v - (float)hh);
            }
            *(f16x4*)(rh + dg * 16 + 4 * ls) = ch;
            *(f16x4*)(rl + dg * 16 + 4 * ls) = cl;
        }
    }
}

extern "C" void kernel_launch(void* const* d_in, const int* in_sizes, int n_in,
                              void* d_out, int out_size, void* d_ws, size_t ws_size,
                              hipStream_t stream)
{
    const float* x  = (const float*)d_in[0];
    const float* Wq = (const float*)d_in[1];
    const float* bq = (const float*)d_in[2];
    const float* Wk = (const float*)d_in[3];
    const float* Wv = (const float*)d_in[4];
    const float* bv = (const float*)d_in[5];
    const float* Wo = (const float*)d_in[6];
    const float* bo = (const float*)d_in[7];
    float* out = (float*)d_out;

    char* p = (char*)d_ws;
    _Float16* Ah  = (_Float16*)p; p += (size_t)NCTX * 1024 * 2;
    _Float16* Al  = (_Float16*)p; p += (size_t)NCTX * 1024 * 2;
    _Float16* Wh  = (_Float16*)p; p += (size_t)4096 * 1024 * 2;
    _Float16* Wl  = (_Float16*)p; p += (size_t)4096 * 1024 * 2;
    _Float16* qh  = (_Float16*)p; p += (size_t)NHEAD * NCTX * 64 * 2;
    _Float16* kh  = (_Float16*)p; p += (size_t)NHEAD * NCTX * 64 * 2;
    _Float16* vt  = (_Float16*)p; p += (size_t)NHEAD * NCTX * 64 * 2;
    _Float16* Ahc = (_Float16*)p; p += (size_t)NCTX * 1024 * 2;
    _Float16* Alc = (_Float16*)p; p += (size_t)NCTX * 1024 * 2;

    presplit_all<<<dim3(NCTX * 128 / 256 + 4096 * 128 / 256), 256, 0, stream>>>(
        x, Wq, Wk, Wv, Wo, Ah, Al, Wh, Wl);
    gemm3p<0><<<dim3(31 * 16), 512, 0, stream>>>(Ah, Al, Wh, Wl, bq, bv, nullptr,
                                                 qh, kh, vt, nullptr);
    attn_kernel<<<dim3(48 * 16), 256, 0, stream>>>(qh, kh, vt, Ahc, Alc);
    gemm3p<1><<<dim3(31 * 8), 512, 0, stream>>>(Ahc, Alc, Wh, Wl, nullptr, nullptr, bo,
                                                nullptr, nullptr, nullptr, out);
}